// Round 1
// baseline (85318.439 us; speedup 1.0000x reference)
//
#include <hip/hip_runtime.h>
#include <hip/hip_cooperative_groups.h>

namespace cg = cooperative_groups;

#define BB 16
#define SS 256
#define NVOCAB 32000
#define NEMB 300

// ---- recurrence kernel geometry ----
#define CHUNK 3            // h-indices per block
#define RROWS (4*CHUNK)    // gate rows per block = 12
#define HT_K 128           // h k-tile
#define HT_LD 132          // padded LDS leading dim for h tile
#define HBSTR (16*1152)    // per-h-buffer stride (floats), fits H<=1150

// ============================ embedding ============================
__global__ void embed_kernel(const int* __restrict__ ids,
                             const float* __restrict__ emb,
                             float* __restrict__ x0) {
    int bs = blockIdx.x;                       // r = b*S+s
    int id = ids[bs];
    const float* row = emb + (size_t)id * NEMB;
    float* out = x0 + (size_t)bs * NEMB;
    const float scale = 17.320508075688772f;   // sqrt(300)
    for (int e = threadIdx.x; e < NEMB; e += blockDim.x)
        out[e] = row[e] * scale;
}

// ============================ GEMM: C = A[M,K] * W[N,K]^T (+bias) ============================
// M fixed = 4096 (B*S), rows r = b*S+s. permuted=1 -> C[(s*B+b)*N+n], else C[r*N+n].
#define TM 64
#define TN 64
#define KT 16
#define LDT 68

__global__ __launch_bounds__(256) void gemm_xw(
        const float* __restrict__ A, const float* __restrict__ W,
        float* __restrict__ C, int N, int K,
        const float* __restrict__ bias_i, const float* __restrict__ bias_h,
        int permuted) {
    __shared__ __align__(16) float As[KT][LDT];
    __shared__ __align__(16) float Bs[KT][LDT];
    const int n0 = blockIdx.x * TN;
    const int m0 = blockIdx.y * TM;
    const int t  = threadIdx.x;
    const int tk = t & 15;
    const int tm = t >> 4;
    const int tx = t & 15;
    const int ty = t >> 4;
    float acc[4][4] = {};

    for (int k0 = 0; k0 < K; k0 += KT) {
        int k = k0 + tk;
        bool kok = (k < K);
        #pragma unroll
        for (int i = 0; i < 4; i++) {
            int m = tm + i * 16;
            As[tk][m] = kok ? A[(size_t)(m0 + m) * K + k] : 0.f;
            int n = n0 + m;
            Bs[tk][m] = (kok && n < N) ? W[(size_t)n * K + k] : 0.f;
        }
        __syncthreads();
        #pragma unroll
        for (int kk = 0; kk < KT; kk++) {
            float4 a = *reinterpret_cast<const float4*>(&As[kk][ty * 4]);
            float4 b = *reinterpret_cast<const float4*>(&Bs[kk][tx * 4]);
            acc[0][0] += a.x * b.x; acc[0][1] += a.x * b.y; acc[0][2] += a.x * b.z; acc[0][3] += a.x * b.w;
            acc[1][0] += a.y * b.x; acc[1][1] += a.y * b.y; acc[1][2] += a.y * b.z; acc[1][3] += a.y * b.w;
            acc[2][0] += a.z * b.x; acc[2][1] += a.z * b.y; acc[2][2] += a.z * b.z; acc[2][3] += a.z * b.w;
            acc[3][0] += a.w * b.x; acc[3][1] += a.w * b.y; acc[3][2] += a.w * b.z; acc[3][3] += a.w * b.w;
        }
        __syncthreads();
    }

    #pragma unroll
    for (int i = 0; i < 4; i++) {
        int m = m0 + ty * 4 + i;
        #pragma unroll
        for (int j = 0; j < 4; j++) {
            int n = n0 + tx * 4 + j;
            if (n < N) {
                float v = acc[i][j];
                if (bias_i) v += bias_i[n] + bias_h[n];
                size_t idx;
                if (permuted) {
                    int b_ = m >> 8;        // S = 256
                    int s_ = m & 255;
                    idx = ((size_t)s_ * BB + b_) * (size_t)N + n;
                } else {
                    idx = (size_t)m * (size_t)N + n;
                }
                C[idx] = v;
            }
        }
    }
}

// ============================ persistent LSTM recurrence ============================
// One cooperative kernel runs all S=256 timesteps of a layer.
// Block owns CHUNK h-indices -> 4*CHUNK rows of W_hh kept in LDS all steps.
// h double-buffered in global ([B][H] per buffer), c kept in LDS.
__global__ __launch_bounds__(256, 2) void lstm_rec(
        const float* __restrict__ Whh,   // [4H][H]
        const float* __restrict__ xg,    // [S][B][4H]
        float* __restrict__ xout,        // [B][S][H]
        float* __restrict__ hbuf,        // 2 * HBSTR floats, layout [B][H]
        int H, int KP /* ceil(H/HT_K)*HT_K */) {
    extern __shared__ float lds[];
    float* Wl   = lds;                     // [RROWS][KP]
    float* ht   = Wl + RROWS * KP;         // [16][HT_LD]
    float* gbuf = ht + 16 * HT_LD;         // [RROWS][16]
    float* cbuf = gbuf + RROWS * 16;       // [CHUNK][16]

    const int t  = threadIdx.x;
    const int h0 = blockIdx.x * CHUNK;
    int nh = H - h0;
    nh = (nh < 0) ? 0 : ((nh > CHUNK) ? CHUNK : nh);

    // Load this block's W_hh rows into LDS (zero-pad k>=H).
    if (nh > 0) {
        for (int idx = t; idx < RROWS * KP; idx += 256) {
            int r = idx / KP;
            int k = idx - r * KP;
            int g = r / CHUNK, l = r - g * CHUNK;
            float v = 0.f;
            if (l < nh && k < H) v = Whh[(size_t)(g * H + h0 + l) * (size_t)H + k];
            Wl[idx] = v;
        }
    }
    if (t < CHUNK * 16) cbuf[t] = 0.f;
    __syncthreads();

    cg::grid_group grid = cg::this_grid();

    const int b    = t & 15;
    const int row  = t >> 4;               // 0..15, rows 12..15 idle
    const int g_   = row / CHUNK;
    const int l_   = row - g_ * CHUNK;
    const bool rowvalid = (row < RROWS) && (l_ < nh) && (nh > 0);
    const float* wrow = Wl + (size_t)(rowvalid ? row : 0) * KP;

    for (int s = 0; s < SS; s++) {
        const float* hc = hbuf + (size_t)(s & 1) * HBSTR;
        float*       hn = hbuf + (size_t)((s + 1) & 1) * HBSTR;
        float a0 = 0.f, a1 = 0.f, a2 = 0.f, a3 = 0.f;

        for (int k0 = 0; k0 < KP; k0 += HT_K) {
            __syncthreads();   // protect ht from previous tile's readers
            for (int idx = t; idx < 16 * HT_K; idx += 256) {
                int bb = idx >> 7;
                int kk = idx & (HT_K - 1);
                int k  = k0 + kk;
                ht[bb * HT_LD + kk] = (k < H) ? hc[(size_t)bb * H + k] : 0.f;
            }
            __syncthreads();
            if (rowvalid) {
                const float* wp = wrow + k0;
                const float* hp = ht + b * HT_LD;
                #pragma unroll 8
                for (int kk = 0; kk < HT_K; kk += 4) {
                    float4 w4 = *reinterpret_cast<const float4*>(wp + kk);
                    float4 h4 = *reinterpret_cast<const float4*>(hp + kk);
                    a0 += w4.x * h4.x;
                    a1 += w4.y * h4.y;
                    a2 += w4.z * h4.z;
                    a3 += w4.w * h4.w;
                }
            }
        }

        if (rowvalid) {
            float dot = (a0 + a1) + (a2 + a3);
            dot += xg[((size_t)s * BB + b) * (size_t)(4 * H) + (size_t)g_ * H + h0 + l_];
            gbuf[row * 16 + b] = dot;
        }
        __syncthreads();

        if (t < nh * 16) {
            int l = t >> 4;
            float gi = gbuf[(0 * CHUNK + l) * 16 + b];
            float gf = gbuf[(1 * CHUNK + l) * 16 + b];
            float gg = gbuf[(2 * CHUNK + l) * 16 + b];
            float go = gbuf[(3 * CHUNK + l) * 16 + b];
            float iv = 1.f / (1.f + expf(-gi));
            float fv = 1.f / (1.f + expf(-gf));
            float gv = tanhf(gg);
            float ov = 1.f / (1.f + expf(-go));
            float c  = fv * cbuf[t] + iv * gv;
            cbuf[t]  = c;
            float hv = ov * tanhf(c);
            hn[(size_t)b * H + (h0 + l)] = hv;
            xout[(size_t)b * ((size_t)SS * H) + (size_t)s * H + (h0 + l)] = hv;
        }

        __threadfence();   // release our h writes to device scope
        grid.sync();
        __threadfence();   // acquire: invalidate L1 before reading other blocks' h
    }
}

// ============================ launch ============================
extern "C" void kernel_launch(void* const* d_in, const int* in_sizes, int n_in,
                              void* d_out, int out_size, void* d_ws, size_t ws_size,
                              hipStream_t stream) {
    const int*   ids  = (const int*)d_in[0];
    const float* emb  = (const float*)d_in[1];
    const float* Wih0 = (const float*)d_in[2];
    const float* Whh0 = (const float*)d_in[3];
    const float* bih0 = (const float*)d_in[4];
    const float* bhh0 = (const float*)d_in[5];
    const float* Wih1 = (const float*)d_in[6];
    const float* Whh1 = (const float*)d_in[7];
    const float* bih1 = (const float*)d_in[8];
    const float* bhh1 = (const float*)d_in[9];
    const float* Wih2 = (const float*)d_in[10];
    const float* Whh2 = (const float*)d_in[11];
    const float* bih2 = (const float*)d_in[12];
    const float* bhh2 = (const float*)d_in[13];
    float* out = (float*)d_out;

    // workspace layout (floats)
    float* ws = (float*)d_ws;
    float* xA = ws;                    // 1,228,800  (x0, later x3)
    float* xB = xA + 1228800;          // 4,710,400  (x1, later x2)
    float* xg = xB + 4710400;          // 18,841,600 (gates, reused per layer)
    float* hb = xg + 18841600;         // 2*HBSTR = 36,864 (h double buffer)

    const int M = BB * SS;             // 4096
    (void)M; (void)in_sizes; (void)n_in; (void)out_size; (void)ws_size;

    // ---- embedding ----
    embed_kernel<<<dim3(BB * SS), dim3(256), 0, stream>>>(ids, emb, xA);

    // ---- layer 0: gates GEMM then recurrence ----
    gemm_xw<<<dim3(72, 64), dim3(256), 0, stream>>>(xA, Wih0, xg, 4600, 300, bih0, bhh0, 1);
    hipMemsetAsync(hb, 0, (size_t)2 * HBSTR * sizeof(float), stream);
    {
        const float* w = Whh0; const float* g = xg; float* xo = xB; float* h = hb;
        int H = 1150, KP = 1152;
        void* args[] = { (void*)&w, (void*)&g, (void*)&xo, (void*)&h, (void*)&H, (void*)&KP };
        size_t ldsb = (size_t)(RROWS * KP + 16 * HT_LD + RROWS * 16 + CHUNK * 16) * sizeof(float);
        hipLaunchCooperativeKernel(reinterpret_cast<void*>(lstm_rec),
                                   dim3(384), dim3(256), args, (unsigned)ldsb, stream);
    }

    // ---- layer 1 ----
    gemm_xw<<<dim3(72, 64), dim3(256), 0, stream>>>(xB, Wih1, xg, 4600, 1150, bih1, bhh1, 1);
    hipMemsetAsync(hb, 0, (size_t)2 * HBSTR * sizeof(float), stream);
    {
        const float* w = Whh1; const float* g = xg; float* xo = xB; float* h = hb;
        int H = 1150, KP = 1152;
        void* args[] = { (void*)&w, (void*)&g, (void*)&xo, (void*)&h, (void*)&H, (void*)&KP };
        size_t ldsb = (size_t)(RROWS * KP + 16 * HT_LD + RROWS * 16 + CHUNK * 16) * sizeof(float);
        hipLaunchCooperativeKernel(reinterpret_cast<void*>(lstm_rec),
                                   dim3(384), dim3(256), args, (unsigned)ldsb, stream);
    }

    // ---- layer 2 ----
    gemm_xw<<<dim3(19, 64), dim3(256), 0, stream>>>(xB, Wih2, xg, 1200, 1150, bih2, bhh2, 1);
    hipMemsetAsync(hb, 0, (size_t)2 * HBSTR * sizeof(float), stream);
    {
        const float* w = Whh2; const float* g = xg; float* xo = xA; float* h = hb;
        int H = 300, KP = 384;
        void* args[] = { (void*)&w, (void*)&g, (void*)&xo, (void*)&h, (void*)&H, (void*)&KP };
        size_t ldsb = (size_t)(RROWS * KP + 16 * HT_LD + RROWS * 16 + CHUNK * 16) * sizeof(float);
        hipLaunchCooperativeKernel(reinterpret_cast<void*>(lstm_rec),
                                   dim3(100), dim3(256), args, (unsigned)ldsb, stream);
    }

    // ---- tied output projection: logits = x3 @ emb^T ----
    gemm_xw<<<dim3(500, 64), dim3(256), 0, stream>>>(xA, emb, out, NVOCAB, NEMB,
                                                     nullptr, nullptr, 0);
}

// Round 2
// 21000.952 us; speedup vs baseline: 4.0626x; 4.0626x over previous
//
#include <hip/hip_runtime.h>

#define BB 16
#define SS 256
#define NVOCAB 32000
#define NEMB 300

// ---- recurrence geometry ----
#define CHUNK 5            // h-indices per block
#define RROWS (4*CHUNK)    // gate rows per block = 20
#define NT 320             // threads per rec block (= RROWS*16)
#define HBSTR (16*1152)    // per-h-buffer stride (floats), fits H<=1150
#define BARSTRIDE 576      // uints per layer barrier region (18 lines * 32)

// ============================ embedding ============================
__global__ void embed_kernel(const int* __restrict__ ids,
                             const float* __restrict__ emb,
                             float* __restrict__ x0) {
    int bs = blockIdx.x;                       // r = b*S+s
    int id = ids[bs];
    const float* row = emb + (size_t)id * NEMB;
    float* out = x0 + (size_t)bs * NEMB;
    const float scale = 17.320508075688772f;   // sqrt(300)
    for (int e = threadIdx.x; e < NEMB; e += blockDim.x)
        out[e] = row[e] * scale;
}

// ============================ GEMM: C = A[M,K] * W[N,K]^T (+bias) ============================
#define TM 64
#define TN 64
#define KT 16
#define LDT 68

__global__ __launch_bounds__(256) void gemm_xw(
        const float* __restrict__ A, const float* __restrict__ W,
        float* __restrict__ C, int N, int K,
        const float* __restrict__ bias_i, const float* __restrict__ bias_h,
        int permuted) {
    __shared__ __align__(16) float As[KT][LDT];
    __shared__ __align__(16) float Bs[KT][LDT];
    const int n0 = blockIdx.x * TN;
    const int m0 = blockIdx.y * TM;
    const int t  = threadIdx.x;
    const int tk = t & 15;
    const int tm = t >> 4;
    const int tx = t & 15;
    const int ty = t >> 4;
    float acc[4][4] = {};

    for (int k0 = 0; k0 < K; k0 += KT) {
        int k = k0 + tk;
        bool kok = (k < K);
        #pragma unroll
        for (int i = 0; i < 4; i++) {
            int m = tm + i * 16;
            As[tk][m] = kok ? A[(size_t)(m0 + m) * K + k] : 0.f;
            int n = n0 + m;
            Bs[tk][m] = (kok && n < N) ? W[(size_t)n * K + k] : 0.f;
        }
        __syncthreads();
        #pragma unroll
        for (int kk = 0; kk < KT; kk++) {
            float4 a = *reinterpret_cast<const float4*>(&As[kk][ty * 4]);
            float4 b = *reinterpret_cast<const float4*>(&Bs[kk][tx * 4]);
            acc[0][0] += a.x * b.x; acc[0][1] += a.x * b.y; acc[0][2] += a.x * b.z; acc[0][3] += a.x * b.w;
            acc[1][0] += a.y * b.x; acc[1][1] += a.y * b.y; acc[1][2] += a.y * b.z; acc[1][3] += a.y * b.w;
            acc[2][0] += a.z * b.x; acc[2][1] += a.z * b.y; acc[2][2] += a.z * b.z; acc[2][3] += a.z * b.w;
            acc[3][0] += a.w * b.x; acc[3][1] += a.w * b.y; acc[3][2] += a.w * b.z; acc[3][3] += a.w * b.w;
        }
        __syncthreads();
    }

    #pragma unroll
    for (int i = 0; i < 4; i++) {
        int m = m0 + ty * 4 + i;
        #pragma unroll
        for (int j = 0; j < 4; j++) {
            int n = n0 + tx * 4 + j;
            if (n < N) {
                float v = acc[i][j];
                if (bias_i) v += bias_i[n] + bias_h[n];
                size_t idx;
                if (permuted) {
                    int b_ = m >> 8;        // S = 256
                    int s_ = m & 255;
                    idx = ((size_t)s_ * BB + b_) * (size_t)N + n;
                } else {
                    idx = (size_t)m * (size_t)N + n;
                }
                C[idx] = v;
            }
        }
    }
}

// ============================ persistent LSTM recurrence ============================
// Grid NB = H/CHUNK blocks (<=256, 1/CU, all co-resident). Block owns 20 gate
// rows of W_hh in LDS for all 256 steps; h exchanged via relaxed agent-scope
// atomics (LLC-coherent, no fences); custom two-level epoch barrier per step.
__global__ __launch_bounds__(NT, 1) void lstm_rec(
        const float* __restrict__ Whh,   // [4H][H]
        const float* __restrict__ xg,    // [S][B][4H]
        float* __restrict__ xout,        // [B][S][H]
        float* __restrict__ hbuf,        // 2 * HBSTR floats, layout [B][H]
        unsigned* __restrict__ bar,      // 18 cachelines: leaf[0..15], root, epoch
        int H, int KP, int KH, int PHASES, int NB) {
    extern __shared__ __align__(16) float lds[];
    const int KPP = KP + 4;
    const int LDH = KH + 4;
    float* Wl   = lds;                     // [RROWS][KPP]
    float* ht   = Wl + RROWS * KPP;        // [16][LDH]
    float* gbuf = ht + 16 * LDH;           // [RROWS][16]
    float* cbuf = gbuf + RROWS * 16;       // [CHUNK][16]

    const int t  = threadIdx.x;
    const int h0 = blockIdx.x * CHUNK;
    const int G4 = 4 * H;
    const int NG = (NB + 15) >> 4;

    // Load this block's W_hh rows into LDS (zero-pad k>=H).
    for (int r = 0; r < RROWS; r++) {
        int g = r / CHUNK, l = r - g * CHUNK;
        const float* src = Whh + (size_t)(g * H + h0 + l) * (size_t)H;
        for (int k = t; k < KP; k += NT)
            Wl[r * KPP + k] = (k < H) ? src[k] : 0.f;
    }
    if (t < CHUNK * 16) cbuf[t] = 0.f;
    __syncthreads();

    const int b    = t & 15;
    const int row  = t >> 4;               // 0..19, all valid
    const int g_   = row / CHUNK;
    const int l_   = row - g_ * CHUNK;
    const float* wrow = Wl + row * KPP;
    const float* hrow = ht + b * LDH;

    for (int s = 0; s < SS; s++) {
        float* hc = hbuf + (size_t)(s & 1) * HBSTR;
        float* hn = hbuf + (size_t)((s + 1) & 1) * HBSTR;
        float a0 = 0.f, a1 = 0.f, a2 = 0.f, a3 = 0.f;

        for (int p = 0; p < PHASES; p++) {
            const int k0 = p * KH;
            __syncthreads();   // ht free to overwrite
            if (s == 0) {
                for (int idx = t; idx < 16 * LDH; idx += NT) lds[(ht - lds) + idx] = 0.f;
            } else {
                for (int bb = 0; bb < 16; bb++) {
                    for (int kk = t; kk < KH; kk += NT) {
                        int k = k0 + kk;
                        float v = 0.f;
                        if (k < H)
                            v = __hip_atomic_load(hc + (size_t)bb * H + k,
                                                  __ATOMIC_RELAXED, __HIP_MEMORY_SCOPE_AGENT);
                        ht[bb * LDH + kk] = v;
                    }
                }
            }
            __syncthreads();
            const float4* wp = reinterpret_cast<const float4*>(wrow + k0);
            const float4* hp = reinterpret_cast<const float4*>(hrow);
            const int nq = KH >> 2;
            #pragma unroll 4
            for (int q = 0; q < nq; q++) {
                float4 w4 = wp[q];
                float4 h4 = hp[q];
                a0 += w4.x * h4.x;
                a1 += w4.y * h4.y;
                a2 += w4.z * h4.z;
                a3 += w4.w * h4.w;
            }
        }

        {
            float dot = (a0 + a1) + (a2 + a3);
            dot += xg[((size_t)s * BB + b) * (size_t)G4 + (size_t)g_ * H + h0 + l_];
            gbuf[row * 16 + b] = dot;
        }
        __syncthreads();

        if (t < CHUNK * 16) {
            int l = t >> 4;
            float gi = gbuf[(0 * CHUNK + l) * 16 + b];
            float gf = gbuf[(1 * CHUNK + l) * 16 + b];
            float gg = gbuf[(2 * CHUNK + l) * 16 + b];
            float go = gbuf[(3 * CHUNK + l) * 16 + b];
            float iv = 1.f / (1.f + expf(-gi));
            float fv = 1.f / (1.f + expf(-gf));
            float gv = tanhf(gg);
            float ov = 1.f / (1.f + expf(-go));
            float c  = fv * cbuf[t] + iv * gv;
            cbuf[t]  = c;
            float hv = ov * tanhf(c);
            __hip_atomic_store(hn + (size_t)b * H + (h0 + l), hv,
                               __ATOMIC_RELAXED, __HIP_MEMORY_SCOPE_AGENT);
            xout[(size_t)b * ((size_t)SS * H) + (size_t)s * H + (h0 + l)] = hv;
        }

        if (s < SS - 1) {
            __syncthreads();   // drains each wave's stores (vmcnt) before arrival
            if (t == 0) {
                const int g = blockIdx.x >> 4;
                const unsigned gsz = (unsigned)min(16, NB - (g << 4));
                const unsigned tgt = (unsigned)(s + 1);
                unsigned a = __hip_atomic_fetch_add(&bar[g * 32], 1u,
                                 __ATOMIC_RELAXED, __HIP_MEMORY_SCOPE_AGENT);
                if (a == gsz * tgt - 1u) {
                    unsigned r = __hip_atomic_fetch_add(&bar[16 * 32], 1u,
                                     __ATOMIC_RELAXED, __HIP_MEMORY_SCOPE_AGENT);
                    if (r == (unsigned)NG * tgt - 1u)
                        __hip_atomic_store(&bar[17 * 32], tgt,
                            __ATOMIC_RELAXED, __HIP_MEMORY_SCOPE_AGENT);
                }
                while (__hip_atomic_load(&bar[17 * 32],
                           __ATOMIC_RELAXED, __HIP_MEMORY_SCOPE_AGENT) < tgt)
                    __builtin_amdgcn_s_sleep(1);
            }
            // next iteration's first __syncthreads releases the block
        }
    }
}

// ============================ launch ============================
extern "C" void kernel_launch(void* const* d_in, const int* in_sizes, int n_in,
                              void* d_out, int out_size, void* d_ws, size_t ws_size,
                              hipStream_t stream) {
    const int*   ids  = (const int*)d_in[0];
    const float* emb  = (const float*)d_in[1];
    const float* Wih0 = (const float*)d_in[2];
    const float* Whh0 = (const float*)d_in[3];
    const float* bih0 = (const float*)d_in[4];
    const float* bhh0 = (const float*)d_in[5];
    const float* Wih1 = (const float*)d_in[6];
    const float* Whh1 = (const float*)d_in[7];
    const float* bih1 = (const float*)d_in[8];
    const float* bhh1 = (const float*)d_in[9];
    const float* Wih2 = (const float*)d_in[10];
    const float* Whh2 = (const float*)d_in[11];
    const float* bih2 = (const float*)d_in[12];
    const float* bhh2 = (const float*)d_in[13];
    float* out = (float*)d_out;

    // workspace layout (floats)
    float* ws = (float*)d_ws;
    float* xA = ws;                        // 1,228,800  (x0, later x3)
    float* xB = xA + 1228800;              // 4,710,400  (x1, later x2)
    float* xg = xB + 4710400;              // 18,841,600 (gates, reused per layer)
    float* hb = xg + 18841600;             // 2*HBSTR = 36,864 (h double buffer)
    unsigned* bar = (unsigned*)(hb + 2 * HBSTR);   // 3 * BARSTRIDE uints
    (void)in_sizes; (void)n_in; (void)out_size; (void)ws_size;

    // zero the barrier counters (replay-safe: captured in the graph)
    hipMemsetAsync(bar, 0, 3 * BARSTRIDE * sizeof(unsigned), stream);

    // ---- embedding ----
    embed_kernel<<<dim3(BB * SS), dim3(256), 0, stream>>>(ids, emb, xA);

    // ---- layer 0 ----
    gemm_xw<<<dim3(72, 64), dim3(256), 0, stream>>>(xA, Wih0, xg, 4600, 300, bih0, bhh0, 1);
    {
        int H = 1150, KP = 1152, KH = 576, PH = 2, NB = 230;
        size_t ldsb = (size_t)(RROWS * (KP + 4) + 16 * (KH + 4) + RROWS * 16 + CHUNK * 16) * sizeof(float);
        lstm_rec<<<dim3(NB), dim3(NT), ldsb, stream>>>(Whh0, xg, xB, hb, bar + 0 * BARSTRIDE,
                                                       H, KP, KH, PH, NB);
    }

    // ---- layer 1 ----
    gemm_xw<<<dim3(72, 64), dim3(256), 0, stream>>>(xB, Wih1, xg, 4600, 1150, bih1, bhh1, 1);
    {
        int H = 1150, KP = 1152, KH = 576, PH = 2, NB = 230;
        size_t ldsb = (size_t)(RROWS * (KP + 4) + 16 * (KH + 4) + RROWS * 16 + CHUNK * 16) * sizeof(float);
        lstm_rec<<<dim3(NB), dim3(NT), ldsb, stream>>>(Whh1, xg, xB, hb, bar + 1 * BARSTRIDE,
                                                       H, KP, KH, PH, NB);
    }

    // ---- layer 2 ----
    gemm_xw<<<dim3(19, 64), dim3(256), 0, stream>>>(xB, Wih2, xg, 1200, 1150, bih2, bhh2, 1);
    {
        int H = 300, KP = 384, KH = 384, PH = 1, NB = 60;
        size_t ldsb = (size_t)(RROWS * (KP + 4) + 16 * (KH + 4) + RROWS * 16 + CHUNK * 16) * sizeof(float);
        lstm_rec<<<dim3(NB), dim3(NT), ldsb, stream>>>(Whh2, xg, xA, hb, bar + 2 * BARSTRIDE,
                                                       H, KP, KH, PH, NB);
    }

    // ---- tied output projection: logits = x3 @ emb^T ----
    gemm_xw<<<dim3(500, 64), dim3(256), 0, stream>>>(xA, emb, out, NVOCAB, NEMB,
                                                     nullptr, nullptr, 0);
}

// Round 3
// 14211.726 us; speedup vs baseline: 6.0034x; 1.4777x over previous
//
#include <hip/hip_runtime.h>

#define BB 16
#define SS 256
#define NVOCAB 32000
#define NEMB 300

// ---- recurrence geometry ----
#define CHUNK 5            // h-indices per block
#define RROWS (4*CHUNK)    // gate rows per block = 20
#define NT 320             // threads per rec block (= RROWS*16)
#define HBSTR (16*1152)    // per-h-buffer stride (floats), fits H<=1150
#define BARSTRIDE 576      // uints per layer barrier region (18 lines * 32)

typedef float f4_t __attribute__((ext_vector_type(4)));

// Coherent (LLC-served) vector load: bypasses per-CU L1 and per-XCD L2 via
// sc0+sc1, same visibility path as agent-scope atomics but 16B coalesced.
// Value is NOT ready until a subsequent s_waitcnt vmcnt — tie via "+v".
__device__ __forceinline__ f4_t llc_load_issue(const float* p) {
    f4_t v;
    asm volatile("global_load_dwordx4 %0, %1, off sc0 sc1"
                 : "=v"(v) : "v"(p));
    return v;
}

// ============================ embedding ============================
__global__ void embed_kernel(const int* __restrict__ ids,
                             const float* __restrict__ emb,
                             float* __restrict__ x0) {
    int bs = blockIdx.x;                       // r = b*S+s
    int id = ids[bs];
    const float* row = emb + (size_t)id * NEMB;
    float* out = x0 + (size_t)bs * NEMB;
    const float scale = 17.320508075688772f;   // sqrt(300)
    for (int e = threadIdx.x; e < NEMB; e += blockDim.x)
        out[e] = row[e] * scale;
}

// ============================ GEMM: C = A[M,K] * W[N,K]^T (+bias) ============================
#define TM 64
#define TN 64
#define KT 16
#define LDT 68

__global__ __launch_bounds__(256) void gemm_xw(
        const float* __restrict__ A, const float* __restrict__ W,
        float* __restrict__ C, int N, int K,
        const float* __restrict__ bias_i, const float* __restrict__ bias_h,
        int permuted) {
    __shared__ __align__(16) float As[KT][LDT];
    __shared__ __align__(16) float Bs[KT][LDT];
    const int n0 = blockIdx.x * TN;
    const int m0 = blockIdx.y * TM;
    const int t  = threadIdx.x;
    const int tk = t & 15;
    const int tm = t >> 4;
    const int tx = t & 15;
    const int ty = t >> 4;
    float acc[4][4] = {};

    for (int k0 = 0; k0 < K; k0 += KT) {
        int k = k0 + tk;
        bool kok = (k < K);
        #pragma unroll
        for (int i = 0; i < 4; i++) {
            int m = tm + i * 16;
            As[tk][m] = kok ? A[(size_t)(m0 + m) * K + k] : 0.f;
            int n = n0 + m;
            Bs[tk][m] = (kok && n < N) ? W[(size_t)n * K + k] : 0.f;
        }
        __syncthreads();
        #pragma unroll
        for (int kk = 0; kk < KT; kk++) {
            float4 a = *reinterpret_cast<const float4*>(&As[kk][ty * 4]);
            float4 b = *reinterpret_cast<const float4*>(&Bs[kk][tx * 4]);
            acc[0][0] += a.x * b.x; acc[0][1] += a.x * b.y; acc[0][2] += a.x * b.z; acc[0][3] += a.x * b.w;
            acc[1][0] += a.y * b.x; acc[1][1] += a.y * b.y; acc[1][2] += a.y * b.z; acc[1][3] += a.y * b.w;
            acc[2][0] += a.z * b.x; acc[2][1] += a.z * b.y; acc[2][2] += a.z * b.z; acc[2][3] += a.z * b.w;
            acc[3][0] += a.w * b.x; acc[3][1] += a.w * b.y; acc[3][2] += a.w * b.z; acc[3][3] += a.w * b.w;
        }
        __syncthreads();
    }

    #pragma unroll
    for (int i = 0; i < 4; i++) {
        int m = m0 + ty * 4 + i;
        #pragma unroll
        for (int j = 0; j < 4; j++) {
            int n = n0 + tx * 4 + j;
            if (n < N) {
                float v = acc[i][j];
                if (bias_i) v += bias_i[n] + bias_h[n];
                size_t idx;
                if (permuted) {
                    int b_ = m >> 8;        // S = 256
                    int s_ = m & 255;
                    idx = ((size_t)s_ * BB + b_) * (size_t)N + n;
                } else {
                    idx = (size_t)m * (size_t)N + n;
                }
                C[idx] = v;
            }
        }
    }
}

// ============================ persistent LSTM recurrence ============================
// Block owns 20 gate rows of W_hh in LDS for all 256 steps. Per step:
// h staged via batched sc0|sc1 dwordx4 loads (LLC path, 4 in flight/thread)
// into a ping-pong LDS tile; phase p+1 loads issued before phase p compute.
// Cross-block h via relaxed agent atomics stores; custom 2-level epoch barrier.
template<int KH, int PH>
__global__ __launch_bounds__(NT, 1) void lstm_rec(
        const float* __restrict__ Whh,   // [4H][H]
        const float* __restrict__ xg,    // [S][B][4H]
        float* __restrict__ xout,        // [B][S][H]
        float* __restrict__ hbuf,        // 2 * HBSTR floats, layout [B][H]
        unsigned* __restrict__ bar,      // leaf[0..15], root, epoch cachelines
        int H, int NB) {
    constexpr int KP  = KH * PH;         // padded K (>= H)
    constexpr int KPP = KP + 4;          // W row stride (pad -> conflict-free)
    constexpr int LDH = KH + 4;          // h tile row stride
    constexpr int NC  = KH / 4;          // f4 chunks per row per phase
    constexpr int TC  = 16 * NC;         // total chunks per phase
    extern __shared__ __align__(16) float lds[];
    float* Wl   = lds;                     // [RROWS][KPP]
    float* htA  = Wl  + RROWS * KPP;       // [16][LDH] ping
    float* htB  = htA + 16 * LDH;          // [16][LDH] pong
    float* gbuf = htB + 16 * LDH;          // [RROWS][16]
    float* cbuf = gbuf + RROWS * 16;       // [CHUNK][16]

    const int t  = threadIdx.x;
    const int h0 = blockIdx.x * CHUNK;
    const int G4 = 4 * H;
    const int NG = (NB + 15) >> 4;

    // Load this block's W_hh rows into LDS (zero-pad k>=H).
    for (int r = 0; r < RROWS; r++) {
        int g = r / CHUNK, l = r - g * CHUNK;
        const float* src = Whh + (size_t)(g * H + h0 + l) * (size_t)H;
        for (int k = t; k < KP; k += NT)
            Wl[r * KPP + k] = (k < H) ? src[k] : 0.f;
    }
    if (t < CHUNK * 16) cbuf[t] = 0.f;
    __syncthreads();

    const int b   = t & 15;
    const int row = t >> 4;               // 0..19
    const int g_  = row / CHUNK;
    const int l_  = row - g_ * CHUNK;
    const float* wrow = Wl + row * KPP;
    const float* xgp  = xg + (size_t)b * G4 + (size_t)g_ * H + (h0 + l_);

    // staging chunk coordinates (compile-time NC division)
    const int i0 = t,           bb0 = i0 / NC, kq0 = i0 - bb0 * NC;
    const int i1 = t +     NT,  bb1 = i1 / NC, kq1 = i1 - bb1 * NC;
    const int i2 = t + 2 * NT,  bb2 = i2 / NC, kq2 = i2 - bb2 * NC;
    const int i3 = t + 3 * NT,  bb3 = i3 / NC, kq3 = i3 - bb3 * NC;

    for (int s = 0; s < SS; s++) {
        const float* hc = hbuf + (size_t)(s & 1) * HBSTR;
        float*       hn = hbuf + (size_t)((s + 1) & 1) * HBSTR;
        float xgv = xgp[(size_t)s * 16 * G4];   // prefetch (L2/L3 path, safe)
        float a0 = 0.f, a1 = 0.f, a2 = 0.f, a3 = 0.f;

        if (s > 0) {
            __syncthreads();   // release: all waves wait for wave0's spin exit
            f4_t v0{}, v1{}, v2{}, v3{};
            {   // issue phase-0 loads
                const float* bp = hc;
                if (i0 < TC) v0 = llc_load_issue(bp + (size_t)bb0 * H + 4 * kq0);
                if (i1 < TC) v1 = llc_load_issue(bp + (size_t)bb1 * H + 4 * kq1);
                if (i2 < TC) v2 = llc_load_issue(bp + (size_t)bb2 * H + 4 * kq2);
                if (i3 < TC) v3 = llc_load_issue(bp + (size_t)bb3 * H + 4 * kq3);
            }
            #pragma unroll
            for (int p = 0; p < PH; p++) {
                asm volatile("s_waitcnt vmcnt(0)"
                             : "+v"(v0), "+v"(v1), "+v"(v2), "+v"(v3) :: "memory");
                float* hd = (p & 1) ? htB : htA;
                if (i0 < TC) *reinterpret_cast<f4_t*>(hd + bb0 * LDH + 4 * kq0) = v0;
                if (i1 < TC) *reinterpret_cast<f4_t*>(hd + bb1 * LDH + 4 * kq1) = v1;
                if (i2 < TC) *reinterpret_cast<f4_t*>(hd + bb2 * LDH + 4 * kq2) = v2;
                if (i3 < TC) *reinterpret_cast<f4_t*>(hd + bb3 * LDH + 4 * kq3) = v3;
                __syncthreads();
                if (p + 1 < PH) {   // issue next phase; latency hides under compute
                    const float* bp = hc + (p + 1) * KH;
                    if (i0 < TC) v0 = llc_load_issue(bp + (size_t)bb0 * H + 4 * kq0);
                    if (i1 < TC) v1 = llc_load_issue(bp + (size_t)bb1 * H + 4 * kq1);
                    if (i2 < TC) v2 = llc_load_issue(bp + (size_t)bb2 * H + 4 * kq2);
                    if (i3 < TC) v3 = llc_load_issue(bp + (size_t)bb3 * H + 4 * kq3);
                }
                const f4_t* wp = reinterpret_cast<const f4_t*>(wrow + p * KH);
                const f4_t* hp = reinterpret_cast<const f4_t*>(((p & 1) ? htB : htA) + b * LDH);
                #pragma unroll 8
                for (int q = 0; q < NC; q++) {
                    f4_t w4 = wp[q];
                    f4_t h4 = hp[q];
                    a0 += w4.x * h4.x;
                    a1 += w4.y * h4.y;
                    a2 += w4.z * h4.z;
                    a3 += w4.w * h4.w;
                }
            }
        }

        float dot = (a0 + a1) + (a2 + a3) + xgv;
        gbuf[row * 16 + b] = dot;
        __syncthreads();

        if (t < CHUNK * 16) {
            int l = t >> 4;
            float gi = gbuf[(0 * CHUNK + l) * 16 + b];
            float gf = gbuf[(1 * CHUNK + l) * 16 + b];
            float gg = gbuf[(2 * CHUNK + l) * 16 + b];
            float go = gbuf[(3 * CHUNK + l) * 16 + b];
            float iv = 1.f / (1.f + expf(-gi));
            float fv = 1.f / (1.f + expf(-gf));
            float gv = tanhf(gg);
            float ov = 1.f / (1.f + expf(-go));
            float c  = fv * cbuf[t] + iv * gv;
            cbuf[t]  = c;
            float hv = ov * tanhf(c);
            __hip_atomic_store(hn + (size_t)b * H + (h0 + l), hv,
                               __ATOMIC_RELAXED, __HIP_MEMORY_SCOPE_AGENT);
            xout[(size_t)b * ((size_t)SS * H) + (size_t)s * H + (h0 + l)] = hv;
        }

        if (s < SS - 1) {
            __syncthreads();   // each wave drains vmcnt before arrival
            if (t == 0) {
                const int g = blockIdx.x >> 4;
                const unsigned gsz = (unsigned)min(16, NB - (g << 4));
                const unsigned tgt = (unsigned)(s + 1);
                unsigned a = __hip_atomic_fetch_add(&bar[g * 32], 1u,
                                 __ATOMIC_RELAXED, __HIP_MEMORY_SCOPE_AGENT);
                if (a == gsz * tgt - 1u) {
                    unsigned r = __hip_atomic_fetch_add(&bar[16 * 32], 1u,
                                     __ATOMIC_RELAXED, __HIP_MEMORY_SCOPE_AGENT);
                    if (r == (unsigned)NG * tgt - 1u)
                        __hip_atomic_store(&bar[17 * 32], tgt,
                            __ATOMIC_RELAXED, __HIP_MEMORY_SCOPE_AGENT);
                }
                while (__hip_atomic_load(&bar[17 * 32],
                           __ATOMIC_RELAXED, __HIP_MEMORY_SCOPE_AGENT) < tgt)
                    __builtin_amdgcn_s_sleep(1);
            }
            // next step's release __syncthreads gates the h loads
        }
    }
}

// ============================ launch ============================
extern "C" void kernel_launch(void* const* d_in, const int* in_sizes, int n_in,
                              void* d_out, int out_size, void* d_ws, size_t ws_size,
                              hipStream_t stream) {
    const int*   ids  = (const int*)d_in[0];
    const float* emb  = (const float*)d_in[1];
    const float* Wih0 = (const float*)d_in[2];
    const float* Whh0 = (const float*)d_in[3];
    const float* bih0 = (const float*)d_in[4];
    const float* bhh0 = (const float*)d_in[5];
    const float* Wih1 = (const float*)d_in[6];
    const float* Whh1 = (const float*)d_in[7];
    const float* bih1 = (const float*)d_in[8];
    const float* bhh1 = (const float*)d_in[9];
    const float* Wih2 = (const float*)d_in[10];
    const float* Whh2 = (const float*)d_in[11];
    const float* bih2 = (const float*)d_in[12];
    const float* bhh2 = (const float*)d_in[13];
    float* out = (float*)d_out;

    // workspace layout (floats)
    float* ws = (float*)d_ws;
    float* xA = ws;                        // 1,228,800  (x0, later x3)
    float* xB = xA + 1228800;              // 4,710,400  (x1, later x2)
    float* xg = xB + 4710400;              // 18,841,600 (gates, reused per layer)
    float* hb = xg + 18841600;             // 2*HBSTR = 36,864 (h double buffer)
    unsigned* bar = (unsigned*)(hb + 2 * HBSTR);   // 3 * BARSTRIDE uints
    (void)in_sizes; (void)n_in; (void)out_size; (void)ws_size;

    // zero the barrier counters (captured in the graph, replay-safe)
    hipMemsetAsync(bar, 0, 3 * BARSTRIDE * sizeof(unsigned), stream);

    // LDS bytes: (RROWS*(KH*PH+4) + 2*16*(KH+4) + RROWS*16 + CHUNK*16) * 4
    const size_t lds01 = (size_t)(RROWS * 1156 + 32 * 292 + RROWS * 16 + CHUNK * 16) * 4;  // 131,456
    const size_t lds2  = (size_t)(RROWS * 388  + 32 * 196 + RROWS * 16 + CHUNK * 16) * 4;  //  57,728

    // ---- embedding ----
    embed_kernel<<<dim3(BB * SS), dim3(256), 0, stream>>>(ids, emb, xA);

    // ---- layer 0 ----
    gemm_xw<<<dim3(72, 64), dim3(256), 0, stream>>>(xA, Wih0, xg, 4600, 300, bih0, bhh0, 1);
    lstm_rec<288, 4><<<dim3(230), dim3(NT), lds01, stream>>>(Whh0, xg, xB, hb,
                                                             bar + 0 * BARSTRIDE, 1150, 230);

    // ---- layer 1 ----
    gemm_xw<<<dim3(72, 64), dim3(256), 0, stream>>>(xB, Wih1, xg, 4600, 1150, bih1, bhh1, 1);
    lstm_rec<288, 4><<<dim3(230), dim3(NT), lds01, stream>>>(Whh1, xg, xB, hb,
                                                             bar + 1 * BARSTRIDE, 1150, 230);

    // ---- layer 2 ----
    gemm_xw<<<dim3(19, 64), dim3(256), 0, stream>>>(xB, Wih2, xg, 1200, 1150, bih2, bhh2, 1);
    lstm_rec<192, 2><<<dim3(60), dim3(NT), lds2, stream>>>(Whh2, xg, xA, hb,
                                                           bar + 2 * BARSTRIDE, 300, 60);

    // ---- tied output projection: logits = x3 @ emb^T ----
    gemm_xw<<<dim3(500, 64), dim3(256), 0, stream>>>(xA, emb, out, NVOCAB, NEMB,
                                                     nullptr, nullptr, 0);
}

// Round 4
// 13667.799 us; speedup vs baseline: 6.2423x; 1.0398x over previous
//
#include <hip/hip_runtime.h>

#define BB 16
#define SS 256
#define NVOCAB 32000
#define NEMB 300

// ---- recurrence geometry ----
#define CHUNK 6            // h-indices per block (multiple of 3 -> chunk-aligned)
#define RROWS 24           // gate rows per block
#define NT 384             // threads per rec block (= RROWS*16)

typedef float f4_t __attribute__((ext_vector_type(4)));
typedef unsigned int u4_t __attribute__((ext_vector_type(4)));

// LLC-coherent 16B ops (sc0|sc1: bypass non-coherent L1/L2, served by MALL).
__device__ __forceinline__ void llc_load_u4(u4_t& v, const u4_t* p) {
    asm volatile("global_load_dwordx4 %0, %1, off sc0 sc1" : "=v"(v) : "v"(p));
}
__device__ __forceinline__ void llc_store_u4(u4_t* p, const u4_t& v) {
    asm volatile("global_store_dwordx4 %0, %1, off sc0 sc1" :: "v"(p), "v"(v) : "memory");
}
__device__ __forceinline__ void anchor_u4(u4_t& v) { asm volatile("" : "+v"(v)); }

// ============================ embedding ============================
__global__ void embed_kernel(const int* __restrict__ ids,
                             const float* __restrict__ emb,
                             float* __restrict__ x0) {
    int bs = blockIdx.x;                       // r = b*S+s
    int id = ids[bs];
    const float* row = emb + (size_t)id * NEMB;
    float* out = x0 + (size_t)bs * NEMB;
    const float scale = 17.320508075688772f;   // sqrt(300)
    for (int e = threadIdx.x; e < NEMB; e += blockDim.x)
        out[e] = row[e] * scale;
}

// ============================ GEMM: C = A[M,K] * W[N,K]^T (+bias) ============================
#define TM 64
#define TN 64
#define KT 16
#define LDT 68

__global__ __launch_bounds__(256) void gemm_xw(
        const float* __restrict__ A, const float* __restrict__ W,
        float* __restrict__ C, int N, int K,
        const float* __restrict__ bias_i, const float* __restrict__ bias_h,
        int permuted) {
    __shared__ __align__(16) float As[KT][LDT];
    __shared__ __align__(16) float Bs[KT][LDT];
    const int n0 = blockIdx.x * TN;
    const int m0 = blockIdx.y * TM;
    const int t  = threadIdx.x;
    const int tk = t & 15;
    const int tm = t >> 4;
    const int tx = t & 15;
    const int ty = t >> 4;
    float acc[4][4] = {};

    for (int k0 = 0; k0 < K; k0 += KT) {
        int k = k0 + tk;
        bool kok = (k < K);
        #pragma unroll
        for (int i = 0; i < 4; i++) {
            int m = tm + i * 16;
            As[tk][m] = kok ? A[(size_t)(m0 + m) * K + k] : 0.f;
            int n = n0 + m;
            Bs[tk][m] = (kok && n < N) ? W[(size_t)n * K + k] : 0.f;
        }
        __syncthreads();
        #pragma unroll
        for (int kk = 0; kk < KT; kk++) {
            float4 a = *reinterpret_cast<const float4*>(&As[kk][ty * 4]);
            float4 b = *reinterpret_cast<const float4*>(&Bs[kk][tx * 4]);
            acc[0][0] += a.x * b.x; acc[0][1] += a.x * b.y; acc[0][2] += a.x * b.z; acc[0][3] += a.x * b.w;
            acc[1][0] += a.y * b.x; acc[1][1] += a.y * b.y; acc[1][2] += a.y * b.z; acc[1][3] += a.y * b.w;
            acc[2][0] += a.z * b.x; acc[2][1] += a.z * b.y; acc[2][2] += a.z * b.z; acc[2][3] += a.z * b.w;
            acc[3][0] += a.w * b.x; acc[3][1] += a.w * b.y; acc[3][2] += a.w * b.z; acc[3][3] += a.w * b.w;
        }
        __syncthreads();
    }

    #pragma unroll
    for (int i = 0; i < 4; i++) {
        int m = m0 + ty * 4 + i;
        #pragma unroll
        for (int j = 0; j < 4; j++) {
            int n = n0 + tx * 4 + j;
            if (n < N) {
                float v = acc[i][j];
                if (bias_i) v += bias_i[n] + bias_h[n];
                size_t idx;
                if (permuted) {
                    int b_ = m >> 8;        // S = 256
                    int s_ = m & 255;
                    idx = ((size_t)s_ * BB + b_) * (size_t)N + n;
                } else {
                    idx = (size_t)m * (size_t)N + n;
                }
                C[idx] = v;
            }
        }
    }
}

// ============================ persistent LSTM recurrence ============================
// Barrier-free: h exchanged as 16B chunks {h0,h1,h2,tag} via single sc0|sc1
// dwordx4 stores (value+flag atomic at LLC). Consumers issue phase-0 loads
// speculatively at the previous step's end and retry only stale chunks.
// Skew is self-bounded (<2) by the all-to-all dot dependency; tags are
// monotonic across layers (TB base) and hx is zeroed once per launch.
template<int NCH, int PH, int E>
__global__ __launch_bounds__(NT, 1) void lstm_rec(
        const float* __restrict__ Whh,   // [4H][H]
        const float* __restrict__ xg,    // [S][B][4H]
        float* __restrict__ xout,        // [B][S][H]
        u4_t* __restrict__ hx,           // [2][16][NCH] chunks
        int H, unsigned TB) {
    constexpr int PHC = NCH / PH;        // chunks per row per phase
    constexpr int KH  = 3 * PHC;         // floats per row per phase
    constexpr int KP  = 3 * NCH;         // padded K
    constexpr int KPP = KP + 4;          // W row stride (dwords)
    constexpr int LDH = KH + 4;          // h tile row stride
    constexpr int NC  = KH / 4;          // f4 iters per phase
    extern __shared__ __align__(16) float lds[];
    float* Wl   = lds;                     // [RROWS][KPP]
    float* ht   = Wl + RROWS * KPP;        // [16][LDH]
    float* gbuf = ht + 16 * LDH;           // [NT]
    float* cbuf = gbuf + NT;               // [96]
    float* hlx  = cbuf + 96;               // [16][CHUNK]

    const int t  = threadIdx.x;
    const int h0 = blockIdx.x * CHUNK;
    const int G4 = 4 * H;

    // Load this block's W_hh rows into LDS (zero-pad k>=H and invalid rows).
    for (int r = 0; r < RROWS; r++) {
        int g = r / CHUNK, l = r - g * CHUNK;
        bool valid = (h0 + l) < H;
        const float* src = Whh + (size_t)(g * H + h0 + l) * (size_t)H;
        for (int k = t; k < KP; k += NT)
            Wl[r * KPP + k] = (valid && k < H) ? src[k] : 0.f;
    }
    if (t < 96) cbuf[t] = 0.f;
    __syncthreads();

    const int b   = t & 15;
    const int row = t >> 4;               // 0..23
    const int g_  = row / CHUNK;
    const int l_  = row - g_ * CHUNK;
    const float* wrow = Wl + row * KPP;
    const float* hrow = ht + b * LDH;
    const float* xgp  = xg + (size_t)b * G4 + (size_t)g_ * H + (h0 + l_);

    // staging chunk coordinates
    int  sb[E]; int sj[E]; bool sa[E];
    #pragma unroll
    for (int e = 0; e < E; e++) {
        int idx = t + e * NT;
        sa[e] = idx < 16 * PHC;
        if (!sa[e]) idx = 0;
        sb[e] = idx / PHC;
        sj[e] = idx - sb[e] * PHC;
    }
    u4_t u[E];

    auto issue = [&](const u4_t* base, int p) {
        #pragma unroll
        for (int e = 0; e < E; e++)
            if (sa[e]) llc_load_u4(u[e], base + sb[e] * NCH + p * PHC + sj[e]);
    };

    for (int s = 0; s < SS; s++) {
        const u4_t* hcb = hx + (size_t)(s & 1) * (16 * NCH);        // consume
        u4_t*       hpb = hx + (size_t)((s + 1) & 1) * (16 * NCH);  // produce
        float xgv = xgp[(size_t)s * 16 * G4];
        float a0 = 0.f, a1 = 0.f, a2 = 0.f, a3 = 0.f;

        if (s > 0) {
            const unsigned tgt = TB + (unsigned)s;
            #pragma unroll
            for (int p = 0; p < PH; p++) {
                // retry-wait the in-flight loads of phase p
                for (;;) {
                    asm volatile("s_waitcnt vmcnt(0)" ::: "memory");
                    #pragma unroll
                    for (int e = 0; e < E; e++) anchor_u4(u[e]);
                    bool pend = false;
                    #pragma unroll
                    for (int e = 0; e < E; e++)
                        if (sa[e] && u[e].w < tgt) {
                            pend = true;
                            llc_load_u4(u[e], hcb + sb[e] * NCH + p * PHC + sj[e]);
                        }
                    if (!pend) break;
                }
                // unpack to LDS tile
                #pragma unroll
                for (int e = 0; e < E; e++)
                    if (sa[e]) {
                        float* d = ht + sb[e] * LDH + 3 * sj[e];
                        d[0] = __uint_as_float(u[e].x);
                        d[1] = __uint_as_float(u[e].y);
                        d[2] = __uint_as_float(u[e].z);
                    }
                __syncthreads();
                if (p + 1 < PH) issue(hcb, p + 1);   // overlap with compute
                const f4_t* wp = reinterpret_cast<const f4_t*>(wrow + p * KH);
                const f4_t* hp = reinterpret_cast<const f4_t*>(hrow);
                #pragma unroll 8
                for (int q = 0; q < NC; q++) {
                    f4_t w4 = wp[q];
                    f4_t h4 = hp[q];
                    a0 += w4.x * h4.x;
                    a1 += w4.y * h4.y;
                    a2 += w4.z * h4.z;
                    a3 += w4.w * h4.w;
                }
                if (p + 1 < PH) __syncthreads();     // tile free for next phase
            }
        }

        float dot = (a0 + a1) + (a2 + a3) + xgv;
        gbuf[t] = dot;                                // gbuf[row*16+b]
        __syncthreads();

        if (t < 96) {
            int l = t >> 4;
            float gi = gbuf[(0 * CHUNK + l) * 16 + b];
            float gf = gbuf[(1 * CHUNK + l) * 16 + b];
            float gg = gbuf[(2 * CHUNK + l) * 16 + b];
            float go = gbuf[(3 * CHUNK + l) * 16 + b];
            float iv = 1.f / (1.f + expf(-gi));
            float fv = 1.f / (1.f + expf(-gf));
            float gv = tanhf(gg);
            float ov = 1.f / (1.f + expf(-go));
            float c  = fv * cbuf[t] + iv * gv;
            cbuf[t]  = c;
            float hv = ov * tanhf(c);
            hv = ((h0 + l) < H) ? hv : 0.f;
            hlx[b * CHUNK + l] = hv;
            if ((h0 + l) < H)
                xout[(size_t)b * ((size_t)SS * H) + (size_t)s * H + (h0 + l)] = hv;
        }
        __syncthreads();

        if (t < 32) {                                  // pack+publish chunks
            int bq = t >> 1, cj = t & 1;
            u4_t pk;
            pk.x = __float_as_uint(hlx[bq * CHUNK + 3 * cj + 0]);
            pk.y = __float_as_uint(hlx[bq * CHUNK + 3 * cj + 1]);
            pk.z = __float_as_uint(hlx[bq * CHUNK + 3 * cj + 2]);
            pk.w = TB + (unsigned)s + 1u;
            llc_store_u4(hpb + bq * NCH + (h0 / 3 + cj), pk);
        }
        if (s + 1 < SS) {                              // speculative phase-0 issue
            const u4_t* hcn = hx + (size_t)((s + 1) & 1) * (16 * NCH);
            issue(hcn, 0);
        }
    }
}

// ============================ launch ============================
extern "C" void kernel_launch(void* const* d_in, const int* in_sizes, int n_in,
                              void* d_out, int out_size, void* d_ws, size_t ws_size,
                              hipStream_t stream) {
    const int*   ids  = (const int*)d_in[0];
    const float* emb  = (const float*)d_in[1];
    const float* Wih0 = (const float*)d_in[2];
    const float* Whh0 = (const float*)d_in[3];
    const float* bih0 = (const float*)d_in[4];
    const float* bhh0 = (const float*)d_in[5];
    const float* Wih1 = (const float*)d_in[6];
    const float* Whh1 = (const float*)d_in[7];
    const float* bih1 = (const float*)d_in[8];
    const float* bhh1 = (const float*)d_in[9];
    const float* Wih2 = (const float*)d_in[10];
    const float* Whh2 = (const float*)d_in[11];
    const float* bih2 = (const float*)d_in[12];
    const float* bhh2 = (const float*)d_in[13];
    float* out = (float*)d_out;

    // workspace layout (floats)
    float* ws = (float*)d_ws;
    float* xA = ws;                        // 1,228,800  (x0, later x3)
    float* xB = xA + 1228800;              // 4,710,400  (x1, later x2)
    float* xg = xB + 4710400;              // 18,841,600 (gates, reused per layer)
    u4_t*  hx = (u4_t*)(xg + 18841600);    // [2][16][384] chunks = 196,608 B
    (void)in_sizes; (void)n_in; (void)out_size; (void)ws_size;

    // zero tags once per launch (graph-captured, replay-safe)
    hipMemsetAsync(hx, 0, (size_t)2 * 16 * 384 * 16, stream);

    // LDS bytes
    const size_t lds01 = (size_t)(RROWS * 1156 + 16 * 292 + NT + 96 + 96) * 4;  // 131,968
    const size_t lds2  = (size_t)(RROWS * 304  + 16 * 304 + NT + 96 + 96) * 4;  //  50,944

    // ---- embedding ----
    embed_kernel<<<dim3(BB * SS), dim3(256), 0, stream>>>(ids, emb, xA);

    // ---- layer 0 ----
    gemm_xw<<<dim3(72, 64), dim3(256), 0, stream>>>(xA, Wih0, xg, 4600, 300, bih0, bhh0, 1);
    lstm_rec<384, 4, 4><<<dim3(192), dim3(NT), lds01, stream>>>(Whh0, xg, xB, hx, 1150, 0u);

    // ---- layer 1 ----
    gemm_xw<<<dim3(72, 64), dim3(256), 0, stream>>>(xB, Wih1, xg, 4600, 1150, bih1, bhh1, 1);
    lstm_rec<384, 4, 4><<<dim3(192), dim3(NT), lds01, stream>>>(Whh1, xg, xB, hx, 1150, 256u);

    // ---- layer 2 ----
    gemm_xw<<<dim3(19, 64), dim3(256), 0, stream>>>(xB, Wih2, xg, 1200, 1150, bih2, bhh2, 1);
    lstm_rec<100, 1, 5><<<dim3(50), dim3(NT), lds2, stream>>>(Whh2, xg, xA, hx, 300, 512u);

    // ---- tied output projection: logits = x3 @ emb^T ----
    gemm_xw<<<dim3(500, 64), dim3(256), 0, stream>>>(xA, emb, out, NVOCAB, NEMB,
                                                     nullptr, nullptr, 0);
}